// Round 1
// baseline (295.202 us; speedup 1.0000x reference)
//
#include <hip/hip_runtime.h>
#include <math.h>

#define HDIM 5
#define GATES 20      // 4*H
#define DDIM 32
#define EDIM 32
#define INDIM 128     // D + 3E
#define VOC 10
#define MT 4          // timesteps per thread

__device__ __forceinline__ float sigmoidf_(float x) {
    return 1.0f / (1.0f + __expf(-x));
}
__device__ __forceinline__ float tanhf_(float x) {
    // tanh(x) = (e^{2x}-1)/(e^{2x}+1); clamp to avoid inf/inf
    x = fminf(15.0f, fmaxf(-15.0f, x));
    float e = __expf(2.0f * x);
    return (e - 1.0f) / (e + 1.0f);
}

__global__ __launch_bounds__(256) void decoder_kernel(
    const float* __restrict__ hidden,   // [2,B,H]
    const float* __restrict__ cell,     // [2,B,H]
    const float* __restrict__ dec_x,    // [T,B,D]
    const int*   __restrict__ mid_cat,  // [T,B]
    const int*   __restrict__ ft_cat,   // [T,B]
    const int*   __restrict__ mf_cat,   // [T,B]
    const float* __restrict__ emb,      // [V,E]
    const float* __restrict__ W_ih0,    // [20,128]
    const float* __restrict__ W_hh0,    // [20,5]
    const float* __restrict__ b_ih0,    // [20]
    const float* __restrict__ b_hh0,    // [20]
    const float* __restrict__ W_ih1,    // [20,5]
    const float* __restrict__ W_hh1,    // [20,5]
    const float* __restrict__ b_ih1,    // [20]
    const float* __restrict__ b_hh1,    // [20]
    float* __restrict__ out,            // [horizon,B,H]
    int B, int horizon, int nch)
{
    __shared__ float sW0[GATES][DDIM];      // W_ih0 cols 0..31 (dec_x part)
    __shared__ float sP[3][VOC][GATES];     // embedding->gate tables
    __shared__ float sW1T[HDIM][GATES];     // W_ih1 transposed [h][r]

    const int tid = threadIdx.x;
    // --- block preamble: fill LDS ---
    for (int i = tid; i < GATES * DDIM; i += blockDim.x) {
        int r = i >> 5, c = i & 31;
        sW0[r][c] = W_ih0[r * INDIM + c];
    }
    for (int i = tid; i < HDIM * GATES; i += blockDim.x) {
        int h = i / GATES, r = i % GATES;
        sW1T[h][r] = W_ih1[r * HDIM + h];
    }
    for (int j = tid; j < 3 * VOC * GATES; j += blockDim.x) {
        int s = j / (VOC * GATES);
        int rem = j % (VOC * GATES);
        int v = rem / GATES, r = rem % GATES;
        const float* ev = emb + v * EDIM;
        const float* wv = W_ih0 + r * INDIM + DDIM + s * EDIM;
        float a = 0.0f;
        #pragma unroll
        for (int e = 0; e < EDIM; ++e) a = fmaf(ev[e], wv[e], a);
        sP[s][v][r] = a;
    }
    __syncthreads();

    const long idx = (long)blockIdx.x * blockDim.x + tid;
    const long total = (long)B * nch;
    if (idx >= total) return;
    const int b  = (int)(idx % B);
    const int tc = (int)(idx / B);
    const int t0 = tc * MT;

    // --- per-b precompute: hh0/hh1 = bias + hidden @ W_hh^T ---
    float hid0[HDIM], hid1[HDIM], c0[HDIM], c1[HDIM];
    #pragma unroll
    for (int h = 0; h < HDIM; ++h) {
        hid0[h] = hidden[(size_t)b * HDIM + h];
        hid1[h] = hidden[((size_t)B + b) * HDIM + h];
        c0[h]   = cell[(size_t)b * HDIM + h];
        c1[h]   = cell[((size_t)B + b) * HDIM + h];
    }
    float hh0[GATES], hh1[GATES];
    #pragma unroll
    for (int r = 0; r < GATES; ++r) {
        float a0 = b_ih0[r] + b_hh0[r];
        float a1 = b_ih1[r] + b_hh1[r];
        #pragma unroll
        for (int h = 0; h < HDIM; ++h) {
            a0 = fmaf(hid0[h], W_hh0[r * HDIM + h], a0);
            a1 = fmaf(hid1[h], W_hh1[r * HDIM + h], a1);
        }
        hh0[r] = a0;
        hh1[r] = a1;
    }

    // --- acc init: hh0 + embedding table lookups ---
    float acc[MT][GATES];
    int tvalid[MT];
    #pragma unroll
    for (int m = 0; m < MT; ++m) {
        int t = t0 + m;
        tvalid[m] = (t < horizon);
        int tt = tvalid[m] ? t : (horizon - 1);
        size_t off = (size_t)tt * B + b;
        int vm = mid_cat[off], vf = ft_cat[off], vmf = mf_cat[off];
        const float4* P0 = (const float4*)sP[0][vm];
        const float4* P1 = (const float4*)sP[1][vf];
        const float4* P2 = (const float4*)sP[2][vmf];
        #pragma unroll
        for (int k = 0; k < 5; ++k) {
            float4 p0 = P0[k], p1 = P1[k], p2 = P2[k];
            acc[m][4 * k + 0] = hh0[4 * k + 0] + p0.x + p1.x + p2.x;
            acc[m][4 * k + 1] = hh0[4 * k + 1] + p0.y + p1.y + p2.y;
            acc[m][4 * k + 2] = hh0[4 * k + 2] + p0.z + p1.z + p2.z;
            acc[m][4 * k + 3] = hh0[4 * k + 3] + p0.w + p1.w + p2.w;
        }
    }

    // --- main matvec: acc += dec_x @ W_ih0[:, :32]^T ---
    const float4* dx4 = (const float4*)dec_x;
    #pragma unroll
    for (int c4 = 0; c4 < DDIM / 4; ++c4) {
        float4 xm[MT];
        #pragma unroll
        for (int m = 0; m < MT; ++m) {
            int t = t0 + m;
            int tt = tvalid[m] ? t : (horizon - 1);
            xm[m] = dx4[((size_t)tt * B + b) * (DDIM / 4) + c4];
        }
        #pragma unroll
        for (int r = 0; r < GATES; ++r) {
            float4 w = ((const float4*)sW0[r])[c4];
            #pragma unroll
            for (int m = 0; m < MT; ++m) {
                float a = acc[m][r];
                a = fmaf(xm[m].x, w.x, a);
                a = fmaf(xm[m].y, w.y, a);
                a = fmaf(xm[m].z, w.z, a);
                a = fmaf(xm[m].w, w.w, a);
                acc[m][r] = a;
            }
        }
    }

    // --- layer 0 nonlinearity -> h1 ---
    float h1[MT][HDIM];
    #pragma unroll
    for (int m = 0; m < MT; ++m) {
        #pragma unroll
        for (int r = 0; r < HDIM; ++r) {
            float ii = sigmoidf_(acc[m][r]);
            float ff = sigmoidf_(acc[m][HDIM + r]);
            float gg = tanhf_(acc[m][2 * HDIM + r]);
            float oo = sigmoidf_(acc[m][3 * HDIM + r]);
            float cn = ff * c0[r] + ii * gg;
            h1[m][r] = oo * tanhf_(cn);
        }
    }

    // --- layer 1 gates: g1 = hh1 + h1 @ W_ih1^T ---
    float g1[MT][GATES];
    #pragma unroll
    for (int m = 0; m < MT; ++m)
        #pragma unroll
        for (int r = 0; r < GATES; ++r) g1[m][r] = hh1[r];
    #pragma unroll
    for (int h = 0; h < HDIM; ++h) {
        #pragma unroll
        for (int k = 0; k < 5; ++k) {
            float4 w = ((const float4*)sW1T[h])[k];
            #pragma unroll
            for (int m = 0; m < MT; ++m) {
                float hv = h1[m][h];
                g1[m][4 * k + 0] = fmaf(hv, w.x, g1[m][4 * k + 0]);
                g1[m][4 * k + 1] = fmaf(hv, w.y, g1[m][4 * k + 1]);
                g1[m][4 * k + 2] = fmaf(hv, w.z, g1[m][4 * k + 2]);
                g1[m][4 * k + 3] = fmaf(hv, w.w, g1[m][4 * k + 3]);
            }
        }
    }

    // --- layer 1 nonlinearity -> output ---
    #pragma unroll
    for (int m = 0; m < MT; ++m) {
        if (!tvalid[m]) continue;
        int t = t0 + m;
        size_t ob = ((size_t)t * B + b) * HDIM;
        #pragma unroll
        for (int r = 0; r < HDIM; ++r) {
            float ii = sigmoidf_(g1[m][r]);
            float ff = sigmoidf_(g1[m][HDIM + r]);
            float gg = tanhf_(g1[m][2 * HDIM + r]);
            float oo = sigmoidf_(g1[m][3 * HDIM + r]);
            float cn = ff * c1[r] + ii * gg;
            out[ob + r] = oo * tanhf_(cn);
        }
    }
}

extern "C" void kernel_launch(void* const* d_in, const int* in_sizes, int n_in,
                              void* d_out, int out_size, void* d_ws, size_t ws_size,
                              hipStream_t stream) {
    // dict order: horizon, hidden, cell, dec_x, mote_id_cat, fault_type_cat,
    // mote_fault_cat, mote_embed, W_ih0, W_hh0, b_ih0, b_hh0, W_ih1, W_hh1, b_ih1, b_hh1
    const float* hidden = (const float*)d_in[1];
    const float* cellp  = (const float*)d_in[2];
    const float* dec_x  = (const float*)d_in[3];
    const int*   midc   = (const int*)d_in[4];
    const int*   ftc    = (const int*)d_in[5];
    const int*   mfc    = (const int*)d_in[6];
    const float* emb    = (const float*)d_in[7];
    const float* W_ih0  = (const float*)d_in[8];
    const float* W_hh0  = (const float*)d_in[9];
    const float* b_ih0  = (const float*)d_in[10];
    const float* b_hh0  = (const float*)d_in[11];
    const float* W_ih1  = (const float*)d_in[12];
    const float* W_hh1  = (const float*)d_in[13];
    const float* b_ih1  = (const float*)d_in[14];
    const float* b_hh1  = (const float*)d_in[15];
    float* out = (float*)d_out;

    int B = in_sizes[1] / (2 * HDIM);           // hidden is [2,B,H]
    int horizon = out_size / (B * HDIM);        // out is [horizon,B,H]
    int nch = (horizon + MT - 1) / MT;
    long total = (long)B * nch;
    int block = 256;
    int grid = (int)((total + block - 1) / block);
    if (grid < 1) grid = 1;

    decoder_kernel<<<grid, block, 0, stream>>>(
        hidden, cellp, dec_x, midc, ftc, mfc, emb,
        W_ih0, W_hh0, b_ih0, b_hh0, W_ih1, W_hh1, b_ih1, b_hh1,
        out, B, horizon, nch);
}

// Round 2
// 126.028 us; speedup vs baseline: 2.3424x; 2.3424x over previous
//
#include <hip/hip_runtime.h>
#include <math.h>

#define HDIM 5
#define GATES 20      // 4*H
#define DDIM 32
#define EDIM 32
#define INDIM 128     // D + 3E
#define VOC 10

__device__ __forceinline__ float sigmoidf_(float x) {
    // 1/(1+e^-x); rcp(inf)=0 handles saturation, no clamp needed
    return __builtin_amdgcn_rcpf(1.0f + __expf(-x));
}
__device__ __forceinline__ float tanhf_(float x) {
    // tanh(x) = 2/(1+e^-2x) - 1
    float e = __expf(-2.0f * x);
    return fmaf(2.0f, __builtin_amdgcn_rcpf(1.0f + e), -1.0f);
}

__global__ __launch_bounds__(256) void decoder_kernel(
    const float* __restrict__ hidden,   // [2,B,H]
    const float* __restrict__ cell,     // [2,B,H]
    const float* __restrict__ dec_x,    // [T,B,D]
    const int*   __restrict__ mid_cat,  // [T,B]
    const int*   __restrict__ ft_cat,   // [T,B]
    const int*   __restrict__ mf_cat,   // [T,B]
    const float* __restrict__ emb,      // [V,E]
    const float* __restrict__ W_ih0,    // [20,128]
    const float* __restrict__ W_hh0,    // [20,5]
    const float* __restrict__ b_ih0,    // [20]
    const float* __restrict__ b_hh0,    // [20]
    const float* __restrict__ W_ih1,    // [20,5]
    const float* __restrict__ W_hh1,    // [20,5]
    const float* __restrict__ b_ih1,    // [20]
    const float* __restrict__ b_hh1,    // [20]
    float* __restrict__ out,            // [horizon,B,H]
    int B, int total)
{
    // Embedding->gate tables: lane-varying lookup, must live in LDS.
    __shared__ float sP[3][VOC][GATES];

    const int tid = threadIdx.x;
    for (int j = tid; j < 3 * VOC * GATES; j += 256) {
        int s = j / (VOC * GATES);
        int rem = j % (VOC * GATES);
        int v = rem / GATES, r = rem % GATES;
        const float* ev = emb + v * EDIM;
        const float* wv = W_ih0 + r * INDIM + DDIM + s * EDIM;
        float a = 0.0f;
        #pragma unroll
        for (int e = 0; e < EDIM; ++e) a = fmaf(ev[e], wv[e], a);
        sP[s][v][r] = a;
    }
    __syncthreads();

    const int idx = blockIdx.x * 256 + tid;   // idx = t*B + b
    if (idx >= total) return;
    const int t = idx / B;
    const int b = idx - t * B;
    (void)t;

    // ---- layer-0 gate pre-activation init: bias + h0@W_hh0^T + embeddings ----
    float acc[GATES];
    {
        float hid0[HDIM];
        #pragma unroll
        for (int h = 0; h < HDIM; ++h) hid0[h] = hidden[(size_t)b * HDIM + h];
        #pragma unroll
        for (int r = 0; r < GATES; ++r) {
            float a = b_ih0[r] + b_hh0[r];    // uniform -> SGPR
            #pragma unroll
            for (int h = 0; h < HDIM; ++h)
                a = fmaf(hid0[h], W_hh0[r * HDIM + h], a);  // W uniform -> SGPR
            acc[r] = a;
        }
        int vm = mid_cat[idx], vf = ft_cat[idx], vmf = mf_cat[idx];
        const float4* P0 = (const float4*)sP[0][vm];
        const float4* P1 = (const float4*)sP[1][vf];
        const float4* P2 = (const float4*)sP[2][vmf];
        #pragma unroll
        for (int k = 0; k < 5; ++k) {
            float4 p0 = P0[k], p1 = P1[k], p2 = P2[k];
            acc[4 * k + 0] += p0.x + p1.x + p2.x;
            acc[4 * k + 1] += p0.y + p1.y + p2.y;
            acc[4 * k + 2] += p0.z + p1.z + p2.z;
            acc[4 * k + 3] += p0.w + p1.w + p2.w;
        }
    }

    // ---- main matvec: acc += dec_x[t,b,:] @ W_ih0[:, :32]^T ----
    {
        const float4* xp = (const float4*)dec_x + (size_t)idx * (DDIM / 4);
        float4 x[DDIM / 4];
        #pragma unroll
        for (int c4 = 0; c4 < DDIM / 4; ++c4) x[c4] = xp[c4];  // 8 loads in flight
        #pragma unroll
        for (int r = 0; r < GATES; ++r) {
            const float* w = W_ih0 + r * INDIM;  // uniform row -> s_load
            float a = acc[r];
            #pragma unroll
            for (int c4 = 0; c4 < DDIM / 4; ++c4) {
                a = fmaf(x[c4].x, w[4 * c4 + 0], a);
                a = fmaf(x[c4].y, w[4 * c4 + 1], a);
                a = fmaf(x[c4].z, w[4 * c4 + 2], a);
                a = fmaf(x[c4].w, w[4 * c4 + 3], a);
            }
            acc[r] = a;
        }
    }

    // ---- layer-0 nonlinearity -> h1 ----
    float h1[HDIM];
    #pragma unroll
    for (int r = 0; r < HDIM; ++r) {
        float c0 = cell[(size_t)b * HDIM + r];
        float ii = sigmoidf_(acc[r]);
        float ff = sigmoidf_(acc[HDIM + r]);
        float gg = tanhf_(acc[2 * HDIM + r]);
        float oo = sigmoidf_(acc[3 * HDIM + r]);
        float cn = fmaf(ff, c0, ii * gg);
        h1[r] = oo * tanhf_(cn);
    }

    // ---- layer-1 gates: g1 = b + h1@W_ih1^T + hid1@W_hh1^T ----
    float g1[GATES];
    {
        float hid1[HDIM];
        #pragma unroll
        for (int h = 0; h < HDIM; ++h) hid1[h] = hidden[((size_t)B + b) * HDIM + h];
        #pragma unroll
        for (int r = 0; r < GATES; ++r) {
            float a = b_ih1[r] + b_hh1[r];
            #pragma unroll
            for (int h = 0; h < HDIM; ++h) {
                a = fmaf(hid1[h], W_hh1[r * HDIM + h], a);
                a = fmaf(h1[h],   W_ih1[r * HDIM + h], a);
            }
            g1[r] = a;
        }
    }

    // ---- layer-1 nonlinearity -> output ----
    #pragma unroll
    for (int r = 0; r < HDIM; ++r) {
        float c1 = cell[((size_t)B + b) * HDIM + r];
        float ii = sigmoidf_(g1[r]);
        float ff = sigmoidf_(g1[HDIM + r]);
        float gg = tanhf_(g1[2 * HDIM + r]);
        float oo = sigmoidf_(g1[3 * HDIM + r]);
        float cn = fmaf(ff, c1, ii * gg);
        out[(size_t)idx * HDIM + r] = oo * tanhf_(cn);
    }
}

extern "C" void kernel_launch(void* const* d_in, const int* in_sizes, int n_in,
                              void* d_out, int out_size, void* d_ws, size_t ws_size,
                              hipStream_t stream) {
    // dict order: horizon, hidden, cell, dec_x, mote_id_cat, fault_type_cat,
    // mote_fault_cat, mote_embed, W_ih0, W_hh0, b_ih0, b_hh0, W_ih1, W_hh1, b_ih1, b_hh1
    const float* hidden = (const float*)d_in[1];
    const float* cellp  = (const float*)d_in[2];
    const float* dec_x  = (const float*)d_in[3];
    const int*   midc   = (const int*)d_in[4];
    const int*   ftc    = (const int*)d_in[5];
    const int*   mfc    = (const int*)d_in[6];
    const float* emb    = (const float*)d_in[7];
    const float* W_ih0  = (const float*)d_in[8];
    const float* W_hh0  = (const float*)d_in[9];
    const float* b_ih0  = (const float*)d_in[10];
    const float* b_hh0  = (const float*)d_in[11];
    const float* W_ih1  = (const float*)d_in[12];
    const float* W_hh1  = (const float*)d_in[13];
    const float* b_ih1  = (const float*)d_in[14];
    const float* b_hh1  = (const float*)d_in[15];
    float* out = (float*)d_out;

    int B = in_sizes[1] / (2 * HDIM);        // hidden is [2,B,H]
    int horizon = out_size / (B * HDIM);     // out is [horizon,B,H]
    int total = horizon * B;                 // one thread per (t,b)
    int grid = (total + 255) / 256;
    if (grid < 1) grid = 1;

    decoder_kernel<<<grid, 256, 0, stream>>>(
        hidden, cellp, dec_x, midc, ftc, mfc, emb,
        W_ih0, W_hh0, b_ih0, b_hh0, W_ih1, W_hh1, b_ih1, b_hh1,
        out, B, total);
}

// Round 3
// 119.181 us; speedup vs baseline: 2.4769x; 1.0574x over previous
//
#include <hip/hip_runtime.h>
#include <math.h>

#define HDIM 5
#define GATES 20      // 4*H
#define DDIM 32
#define EDIM 32
#define INDIM 128     // D + 3E
#define VOC 10
#define SPN (3 * VOC * GATES)   // 600 floats: embedding->gate tables
#define HH_OFF 1024             // float offset of hh tables in ws

__device__ __forceinline__ float sigmoidf_(float x) {
    // 1/(1+e^-x); rcp(inf)=0 handles saturation
    return __builtin_amdgcn_rcpf(1.0f + __expf(-x));
}
__device__ __forceinline__ float tanhf_(float x) {
    // tanh(x) = 2/(1+e^-2x) - 1
    float e = __expf(-2.0f * x);
    return fmaf(2.0f, __builtin_amdgcn_rcpf(1.0f + e), -1.0f);
}

// One small dispatch: sP[600] = emb->gate dot tables; hh[2][B][20] = bias + h@W_hh^T.
__global__ __launch_bounds__(256) void precompute_kernel(
    const float* __restrict__ hidden,   // [2,B,H]
    const float* __restrict__ emb,      // [V,E]
    const float* __restrict__ W_ih0,    // [20,128]
    const float* __restrict__ W_hh0, const float* __restrict__ b_ih0,
    const float* __restrict__ b_hh0,
    const float* __restrict__ W_hh1, const float* __restrict__ b_ih1,
    const float* __restrict__ b_hh1,
    float* __restrict__ ws, int B)
{
    int gid = blockIdx.x * 256 + threadIdx.x;
    if (gid < SPN) {
        int s = gid / (VOC * GATES);
        int rem = gid % (VOC * GATES);
        int v = rem / GATES, r = rem % GATES;
        const float4* ev = (const float4*)(emb + v * EDIM);
        const float4* wv = (const float4*)(W_ih0 + r * INDIM + DDIM + s * EDIM);
        float a = 0.0f;
        #pragma unroll
        for (int k = 0; k < EDIM / 4; ++k) {
            float4 e4 = ev[k], w4 = wv[k];
            a = fmaf(e4.x, w4.x, a); a = fmaf(e4.y, w4.y, a);
            a = fmaf(e4.z, w4.z, a); a = fmaf(e4.w, w4.w, a);
        }
        ws[gid] = a;
    }
    if (gid < B) {
        float h0[HDIM], h1v[HDIM];
        #pragma unroll
        for (int h = 0; h < HDIM; ++h) {
            h0[h]  = hidden[(size_t)gid * HDIM + h];
            h1v[h] = hidden[((size_t)B + gid) * HDIM + h];
        }
        #pragma unroll
        for (int r = 0; r < GATES; ++r) {
            float a0 = b_ih0[r] + b_hh0[r];
            float a1 = b_ih1[r] + b_hh1[r];
            #pragma unroll
            for (int h = 0; h < HDIM; ++h) {
                a0 = fmaf(h0[h],  W_hh0[r * HDIM + h], a0);
                a1 = fmaf(h1v[h], W_hh1[r * HDIM + h], a1);
            }
            ws[HH_OFF + (size_t)gid * GATES + r] = a0;
            ws[HH_OFF + (size_t)(B + gid) * GATES + r] = a1;
        }
    }
}

__global__ __launch_bounds__(256, 4) void decoder_kernel(
    const float* __restrict__ cell,     // [2,B,H]
    const float* __restrict__ dec_x,    // [T,B,D]
    const int*   __restrict__ midc,     // [T,B]
    const int*   __restrict__ ftc,      // [T,B]
    const int*   __restrict__ mfc,      // [T,B]
    const float* __restrict__ W_ih0,    // [20,128] (only cols 0..31 used here)
    const float* __restrict__ W_ih1,    // [20,5]
    const float* __restrict__ ws,       // sP + hh tables
    float* __restrict__ out,            // [horizon,B,H]
    int B, int total)
{
    __shared__ float sP[SPN];
    for (int j = threadIdx.x; j < SPN; j += 256) sP[j] = ws[j];
    __syncthreads();

    const int idx = blockIdx.x * 256 + threadIdx.x;   // idx = t*B + b
    if (idx >= total) return;
    const int t = idx / B;
    const int b = idx - t * B;
    (void)t;

    // Issue the long-latency loads up front.
    const float4* xp = (const float4*)dec_x + (size_t)idx * (DDIM / 4);
    float4 x[DDIM / 4];
    #pragma unroll
    for (int k = 0; k < DDIM / 4; ++k) x[k] = xp[k];

    const int vm = midc[idx], vf = ftc[idx], vmf = mfc[idx];

    // acc = hh0[b]  (bias + h0@W_hh0^T, precomputed)
    float acc[GATES];
    const float4* hh0p = (const float4*)(ws + HH_OFF + (size_t)b * GATES);
    #pragma unroll
    for (int k = 0; k < 5; ++k) {
        float4 h4 = hh0p[k];
        acc[4 * k + 0] = h4.x; acc[4 * k + 1] = h4.y;
        acc[4 * k + 2] = h4.z; acc[4 * k + 3] = h4.w;
    }

    // acc += embedding->gate table entries (LDS gather; rows are 80B apart, 16B aligned)
    const float4* P0 = (const float4*)(sP + vm * GATES);
    const float4* P1 = (const float4*)(sP + VOC * GATES + vf * GATES);
    const float4* P2 = (const float4*)(sP + 2 * VOC * GATES + vmf * GATES);
    #pragma unroll
    for (int k = 0; k < 5; ++k) {
        float4 p0 = P0[k], p1 = P1[k], p2 = P2[k];
        acc[4 * k + 0] += p0.x + p1.x + p2.x;
        acc[4 * k + 1] += p0.y + p1.y + p2.y;
        acc[4 * k + 2] += p0.z + p1.z + p2.z;
        acc[4 * k + 3] += p0.w + p1.w + p2.w;
    }

    // acc += dec_x[t,b,:] @ W_ih0[:, :32]^T   (weights via scalar pipe)
    #pragma unroll
    for (int r = 0; r < GATES; ++r) {
        const float* w = W_ih0 + r * INDIM;   // wave-uniform -> s_load
        float a = acc[r];
        #pragma unroll
        for (int k = 0; k < DDIM / 4; ++k) {
            a = fmaf(x[k].x, w[4 * k + 0], a);
            a = fmaf(x[k].y, w[4 * k + 1], a);
            a = fmaf(x[k].z, w[4 * k + 2], a);
            a = fmaf(x[k].w, w[4 * k + 3], a);
        }
        acc[r] = a;
    }

    // layer-0 nonlinearity -> h1
    float h1[HDIM];
    #pragma unroll
    for (int r = 0; r < HDIM; ++r) {
        float c0 = cell[(size_t)b * HDIM + r];
        float ii = sigmoidf_(acc[r]);
        float ff = sigmoidf_(acc[HDIM + r]);
        float gg = tanhf_(acc[2 * HDIM + r]);
        float oo = sigmoidf_(acc[3 * HDIM + r]);
        float cn = fmaf(ff, c0, ii * gg);
        h1[r] = oo * tanhf_(cn);
    }

    // layer-1 gates: g1 = hh1[b] + h1 @ W_ih1^T
    float g1[GATES];
    const float4* hh1p = (const float4*)(ws + HH_OFF + (size_t)(B + b) * GATES);
    #pragma unroll
    for (int k = 0; k < 5; ++k) {
        float4 h4 = hh1p[k];
        g1[4 * k + 0] = h4.x; g1[4 * k + 1] = h4.y;
        g1[4 * k + 2] = h4.z; g1[4 * k + 3] = h4.w;
    }
    #pragma unroll
    for (int r = 0; r < GATES; ++r) {
        float a = g1[r];
        #pragma unroll
        for (int h = 0; h < HDIM; ++h)
            a = fmaf(h1[h], W_ih1[r * HDIM + h], a);   // uniform -> s_load
        g1[r] = a;
    }

    // layer-1 nonlinearity -> out
    #pragma unroll
    for (int r = 0; r < HDIM; ++r) {
        float c1 = cell[((size_t)B + b) * HDIM + r];
        float ii = sigmoidf_(g1[r]);
        float ff = sigmoidf_(g1[HDIM + r]);
        float gg = tanhf_(g1[2 * HDIM + r]);
        float oo = sigmoidf_(g1[3 * HDIM + r]);
        float cn = fmaf(ff, c1, ii * gg);
        out[(size_t)idx * HDIM + r] = oo * tanhf_(cn);
    }
}

extern "C" void kernel_launch(void* const* d_in, const int* in_sizes, int n_in,
                              void* d_out, int out_size, void* d_ws, size_t ws_size,
                              hipStream_t stream) {
    // dict order: horizon, hidden, cell, dec_x, mote_id_cat, fault_type_cat,
    // mote_fault_cat, mote_embed, W_ih0, W_hh0, b_ih0, b_hh0, W_ih1, W_hh1, b_ih1, b_hh1
    const float* hidden = (const float*)d_in[1];
    const float* cellp  = (const float*)d_in[2];
    const float* dec_x  = (const float*)d_in[3];
    const int*   midc   = (const int*)d_in[4];
    const int*   ftc    = (const int*)d_in[5];
    const int*   mfc    = (const int*)d_in[6];
    const float* emb    = (const float*)d_in[7];
    const float* W_ih0  = (const float*)d_in[8];
    const float* W_hh0  = (const float*)d_in[9];
    const float* b_ih0  = (const float*)d_in[10];
    const float* b_hh0  = (const float*)d_in[11];
    const float* W_ih1  = (const float*)d_in[12];
    const float* W_hh1  = (const float*)d_in[13];
    const float* b_ih1  = (const float*)d_in[14];
    const float* b_hh1  = (const float*)d_in[15];
    float* out = (float*)d_out;
    float* ws  = (float*)d_ws;

    int B = in_sizes[1] / (2 * HDIM);        // hidden is [2,B,H]
    int horizon = out_size / (B * HDIM);     // out is [horizon,B,H]
    int total = horizon * B;

    int pre_n = (B > SPN ? B : SPN);
    int pre_grid = (pre_n + 255) / 256;
    precompute_kernel<<<pre_grid, 256, 0, stream>>>(
        hidden, emb, W_ih0, W_hh0, b_ih0, b_hh0, W_hh1, b_ih1, b_hh1, ws, B);

    int grid = (total + 255) / 256;
    if (grid < 1) grid = 1;
    decoder_kernel<<<grid, 256, 0, stream>>>(
        cellp, dec_x, midc, ftc, mfc, W_ih0, W_ih1, ws, out, B, total);
}